// Round 7
// baseline (55.913 us; speedup 1.0000x reference)
//
#include <hip/hip_runtime.h>
#include <hip/hip_bf16.h>

// GridToMeshEncoder R7: fused kernel, gather straight into GEMM1 B-fragments
// (no comb LDS, one barrier total).
//   phase1: per-wave gather of its 16 points into bf16 B-frags (registers)
//   phase2: GEMM1 h^T = W1^T * comb^T per wave (16 hid-tiles x 3 ks) -> hbuf LDS
//   phase3: GEMM2^T out^T = W2^T * h^T -> float4 stores
// prep kernel packs W1/W2 into MFMA fragment order (L2-resident, ~180 KB).

constexpr int kNLat  = 721;
constexpr int kNLon  = 1440;
constexpr long long kNPix = (long long)kNLat * kNLon;   // 1038240
constexpr int kMesh  = 40962;
constexpr int kCIn   = 64;
constexpr int kFeat  = 4;
constexpr int kDIn   = kCIn + kFeat;                    // 68
constexpr int kHid   = 256;
constexpr int kOut   = 256;
constexpr int kBatch = 2;

constexpr int kPts    = kBatch * kMesh;                 // 81924
constexpr int kPtsPad = (kPts + 63) & ~63;              // 81984

typedef __attribute__((ext_vector_type(8))) short bf16x8;
typedef __attribute__((ext_vector_type(4))) float f32x4;

// ws layout (ushort units): wsA1 = W1^T A-frags [rt:16][ks:3][lane:64][j:8]
//                           wsB2 = W2   frags   [ct:16][ks:8][lane:64][j:8]
constexpr int    WSA1_N   = 16 * 3 * 64 * 8;            // 24576
constexpr int    WSB2_N   = 16 * 8 * 64 * 8;            // 65536
constexpr size_t WS_BYTES = (size_t)(WSA1_N + WSB2_N) * 2;  // 180224

constexpr int MP    = 64;                       // points per block
constexpr int NBLKB = kPtsPad / MP;             // 1281
constexpr int HSTR  = 256;                      // hbuf row stride (ushort): 512 B

__device__ inline ushort f2b(float v) {
    __hip_bfloat16 h = __float2bfloat16(v);
    return *reinterpret_cast<ushort*>(&h);
}

// XOR swizzle on 16B granules within a 512B row (proven R6; reads/writes paired)
__device__ inline int hswz(int r, int c) { return r * HSTR + (c ^ ((r & 7) << 3)); }

// ---------------- prep: pack W1/W2 into frag-ordered bf16 ----------------
__global__ __launch_bounds__(256)
void g2m_prep(const float* __restrict__ W1, const float* __restrict__ W2,
              ushort* __restrict__ ws) {
    const int tid = blockIdx.x * 256 + threadIdx.x;
    if (tid < 3072) {                       // wsA1: A[i=hid][k] = W1[k][hid]
        const int l  = tid & 63;
        const int g  = tid >> 6;            // g = rt*3 + ks
        const int ks = g % 3;
        const int rt = g / 3;
        const int hid = rt * 16 + (l & 15);
        const int k0  = ks * 32 + (l >> 4) * 8;
        ushort tmp[8];
        #pragma unroll
        for (int j = 0; j < 8; ++j) {
            const int k = k0 + j;
            tmp[j] = f2b(k < kDIn ? W1[(size_t)k * kHid + hid] : 0.f);
        }
        *reinterpret_cast<bf16x8*>(ws + (size_t)tid * 8) =
            *reinterpret_cast<bf16x8*>(tmp);
    } else if (tid < 11264) {               // wsB2: [ct][ks][lane][8] = W2[k][col]
        const int q  = tid - 3072;
        const int l  = q & 63;
        const int g  = q >> 6;              // g = ct*8 + ks
        const int ks = g % 8;
        const int ct = g / 8;
        const int col = ct * 16 + (l & 15);
        const int k0  = ks * 32 + (l >> 4) * 8;
        ushort tmp[8];
        #pragma unroll
        for (int j = 0; j < 8; ++j) {
            const int k = k0 + j;
            tmp[j] = f2b(W2[(size_t)k * kOut + col]);
        }
        *reinterpret_cast<bf16x8*>(ws + (size_t)(WSA1_N + q * 8)) =
            *reinterpret_cast<bf16x8*>(tmp);
    }
}

// ---------------- fused: gather->frags -> GEMM1 -> GEMM2^T -> out ----------------
__global__ __launch_bounds__(256, 4)
void g2m_fused4(const float* __restrict__ grid,
                const float* __restrict__ mfeat,
                const int*   __restrict__ indices,
                const float* __restrict__ weights,
                const float* __restrict__ b1,
                const float* __restrict__ b2,
                const ushort* __restrict__ ws,
                float* __restrict__ out)
{
    __shared__ __align__(16) ushort hbuf[MP * HSTR];    // 32768 B

    const int t    = threadIdx.x;
    const int lane = t & 63;
    const int w    = t >> 6;                    // wave id 0..3
    const int p0   = blockIdx.x * MP;
    const int l15  = lane & 15;
    const int l4   = lane >> 4;

    // ---- phase 1: gather this wave's 16 points straight into B-frags ----
    // lane l supplies k = ks*32 + l4*8 + j  of point (w*16 + l15).
    bf16x8 bA[3];
    {
        const int p = p0 + w * 16 + l15;
        float4 r0a{0,0,0,0}, r0b{0,0,0,0}, r0c{0,0,0,0}, r0d{0,0,0,0};
        float4 r1a{0,0,0,0}, r1b{0,0,0,0}, r1c{0,0,0,0}, r1d{0,0,0,0};
        float4 r2a{0,0,0,0}, r2b{0,0,0,0}, r2c{0,0,0,0}, r2d{0,0,0,0};
        float4 r3a{0,0,0,0}, r3b{0,0,0,0}, r3c{0,0,0,0}, r3d{0,0,0,0};
        float4 wt{0,0,0,0}, mfv{0,0,0,0};
        if (p < kPts) {
            const int b = (p >= kMesh) ? 1 : 0;
            const int m = p - b * kMesh;
            const int4 id = *reinterpret_cast<const int4*>(indices + (size_t)m * 4);
            wt = *reinterpret_cast<const float4*>(weights + (size_t)m * 4);
            const float* gb = grid + (size_t)b * (size_t)(kNPix * kCIn);
            const int o0 = l4 * 8;              // ks=0 half: channels o0..o0+7
            const int o1 = 32 + l4 * 8;         // ks=1 half
            const float* c0 = gb + (size_t)id.x * kCIn;
            const float* c1 = gb + (size_t)id.y * kCIn;
            const float* c2 = gb + (size_t)id.z * kCIn;
            const float* c3 = gb + (size_t)id.w * kCIn;
            r0a = *reinterpret_cast<const float4*>(c0 + o0);
            r0b = *reinterpret_cast<const float4*>(c0 + o0 + 4);
            r0c = *reinterpret_cast<const float4*>(c0 + o1);
            r0d = *reinterpret_cast<const float4*>(c0 + o1 + 4);
            r1a = *reinterpret_cast<const float4*>(c1 + o0);
            r1b = *reinterpret_cast<const float4*>(c1 + o0 + 4);
            r1c = *reinterpret_cast<const float4*>(c1 + o1);
            r1d = *reinterpret_cast<const float4*>(c1 + o1 + 4);
            r2a = *reinterpret_cast<const float4*>(c2 + o0);
            r2b = *reinterpret_cast<const float4*>(c2 + o0 + 4);
            r2c = *reinterpret_cast<const float4*>(c2 + o1);
            r2d = *reinterpret_cast<const float4*>(c2 + o1 + 4);
            r3a = *reinterpret_cast<const float4*>(c3 + o0);
            r3b = *reinterpret_cast<const float4*>(c3 + o0 + 4);
            r3c = *reinterpret_cast<const float4*>(c3 + o1);
            r3d = *reinterpret_cast<const float4*>(c3 + o1 + 4);
            if (l4 == 0) mfv = *reinterpret_cast<const float4*>(mfeat + (size_t)m * 4);
        }
        // weighted sums -> bf16 fragments
        ushort f0[8], f1[8], f2[8];
        #pragma unroll
        for (int j = 0; j < 4; ++j) {
            const float a0 = (&r0a.x)[j], a1 = (&r1a.x)[j], a2 = (&r2a.x)[j], a3 = (&r3a.x)[j];
            f0[j] = f2b(fmaf(wt.x, a0, fmaf(wt.y, a1, fmaf(wt.z, a2, wt.w * a3))));
            const float b0 = (&r0b.x)[j], b1v = (&r1b.x)[j], b2v = (&r2b.x)[j], b3 = (&r3b.x)[j];
            f0[4 + j] = f2b(fmaf(wt.x, b0, fmaf(wt.y, b1v, fmaf(wt.z, b2v, wt.w * b3))));
            const float c0v = (&r0c.x)[j], c1v = (&r1c.x)[j], c2v = (&r2c.x)[j], c3v = (&r3c.x)[j];
            f1[j] = f2b(fmaf(wt.x, c0v, fmaf(wt.y, c1v, fmaf(wt.z, c2v, wt.w * c3v))));
            const float d0 = (&r0d.x)[j], d1 = (&r1d.x)[j], d2 = (&r2d.x)[j], d3 = (&r3d.x)[j];
            f1[4 + j] = f2b(fmaf(wt.x, d0, fmaf(wt.y, d1, fmaf(wt.z, d2, wt.w * d3))));
            f2[j]     = f2b((&mfv.x)[j]);      // k=64..67 (only l4==0 nonzero)
            f2[4 + j] = 0;                     // k-pad
        }
        bA[0] = *reinterpret_cast<bf16x8*>(f0);
        bA[1] = *reinterpret_cast<bf16x8*>(f1);
        bA[2] = *reinterpret_cast<bf16x8*>(f2);
    }

    // ---- phase 2: GEMM1  h^T = W1^T @ combfrag, all 16 hid-tiles ----
    {
        #pragma unroll
        for (int rt = 0; rt < 16; ++rt) {
            f32x4 acc = (f32x4)0.f;
            #pragma unroll
            for (int ks = 0; ks < 3; ++ks) {
                const bf16x8 af = *reinterpret_cast<const bf16x8*>(
                        ws + (size_t)((rt * 3 + ks) * 64 + lane) * 8);
                acc = __builtin_amdgcn_mfma_f32_16x16x32_bf16(af, bA[ks], acc, 0, 0, 0);
            }
            // bias + relu -> hbuf[pt][hid] (bf16, swizzled)
            const int hid0 = rt * 16 + l4 * 4;
            const float4 bv = *reinterpret_cast<const float4*>(b1 + hid0);
            ushort4 hv;
            hv.x = f2b(fmaxf(acc[0] + bv.x, 0.f));
            hv.y = f2b(fmaxf(acc[1] + bv.y, 0.f));
            hv.z = f2b(fmaxf(acc[2] + bv.z, 0.f));
            hv.w = f2b(fmaxf(acc[3] + bv.w, 0.f));
            *reinterpret_cast<ushort4*>(&hbuf[hswz(w * 16 + l15, hid0)]) = hv;
        }
    }
    __syncthreads();

    // ---- phase 3: GEMM2 transposed  out^T = W2^T @ h^T ----
    {
        f32x4 acc2[4][4];                       // [mt(pt-tile)][c(outcol-tile)]
        #pragma unroll
        for (int mt = 0; mt < 4; ++mt)
            #pragma unroll
            for (int c = 0; c < 4; ++c) acc2[mt][c] = (f32x4)0.f;

        #pragma unroll
        for (int ks = 0; ks < 8; ++ks) {
            bf16x8 hf[4], wf[4];
            #pragma unroll
            for (int mt = 0; mt < 4; ++mt)
                hf[mt] = *reinterpret_cast<const bf16x8*>(
                            &hbuf[hswz(mt * 16 + l15, ks * 32 + l4 * 8)]);
            #pragma unroll
            for (int c = 0; c < 4; ++c) {
                const int ct = w * 4 + c;
                wf[c] = *reinterpret_cast<const bf16x8*>(
                            ws + (size_t)(WSA1_N + ((ct * 8 + ks) * 64 + lane) * 8));
            }
            #pragma unroll
            for (int mt = 0; mt < 4; ++mt)
                #pragma unroll
                for (int c = 0; c < 4; ++c)
                    acc2[mt][c] = __builtin_amdgcn_mfma_f32_16x16x32_bf16(
                                      wf[c], hf[mt], acc2[mt][c], 0, 0, 0);
        }

        // epilogue: lane holds 4 consecutive out cols for one point -> float4
        #pragma unroll
        for (int c = 0; c < 4; ++c) {
            const int col0 = (w * 4 + c) * 16 + l4 * 4;
            const float4 bv = *reinterpret_cast<const float4*>(b2 + col0);
            #pragma unroll
            for (int mt = 0; mt < 4; ++mt) {
                const int p = p0 + mt * 16 + l15;
                if (p < kPts) {
                    float4 o;
                    o.x = acc2[mt][c][0] + bv.x;
                    o.y = acc2[mt][c][1] + bv.y;
                    o.z = acc2[mt][c][2] + bv.z;
                    o.w = acc2[mt][c][3] + bv.w;
                    *reinterpret_cast<float4*>(out + (size_t)p * kOut + col0) = o;
                }
            }
        }
    }
}

extern "C" void kernel_launch(void* const* d_in, const int* in_sizes, int n_in,
                              void* d_out, int out_size, void* d_ws, size_t ws_size,
                              hipStream_t stream) {
    const float* grid    = (const float*)d_in[0];
    const float* mfeat   = (const float*)d_in[1];
    const int*   indices = (const int*)d_in[2];
    const float* weights = (const float*)d_in[3];
    const float* W1      = (const float*)d_in[4];
    const float* b1      = (const float*)d_in[5];
    const float* W2      = (const float*)d_in[6];
    const float* b2      = (const float*)d_in[7];
    float* o = (float*)d_out;

    if (ws_size >= WS_BYTES) {
        ushort* ws = (ushort*)d_ws;
        g2m_prep<<<44, 256, 0, stream>>>(W1, W2, ws);
        g2m_fused4<<<NBLKB, 256, 0, stream>>>(grid, mfeat, indices, weights,
                                              b1, b2, ws, o);
    }
}